// Round 1
// baseline (4062.199 us; speedup 1.0000x reference)
//
#include <hip/hip_runtime.h>
#include <math.h>

#define EPS   1e-6f
#define NDIM  8192
#define NSTEPS 50
// exp(-C/gamma) = exp2(C * SCALE), SCALE = -log2(e)/0.1
#define SCALE (-14.426950408889634f)
// K~ = 256 * exp(-C/gamma): fits OCP e4m3 normal range [2^-6, 448] almost fully
#define KLOG2 8.0f
#define KSCALE 256.0f

typedef float v2f __attribute__((ext_vector_type(2)));

__device__ __forceinline__ v2f cvt2lo(unsigned w) {
  return __builtin_amdgcn_cvt_pk_f32_fp8(w, false);   // bytes 0,1
}
__device__ __forceinline__ v2f cvt2hi(unsigned w) {
  return __builtin_amdgcn_cvt_pk_f32_fp8(w, true);    // bytes 2,3
}

// 16 fp8 (uint4) dotted with 16 b-values (4 float4)
__device__ __forceinline__ float dot16(uint4 q, float4 b0, float4 b1,
                                       float4 b2, float4 b3) {
  v2f f; float acc;
  f = cvt2lo(q.x); acc  = f.x * b0.x + f.y * b0.y;
  f = cvt2hi(q.x); acc += f.x * b0.z + f.y * b0.w;
  f = cvt2lo(q.y); acc += f.x * b1.x + f.y * b1.y;
  f = cvt2hi(q.y); acc += f.x * b1.z + f.y * b1.w;
  f = cvt2lo(q.z); acc += f.x * b2.x + f.y * b2.y;
  f = cvt2hi(q.z); acc += f.x * b2.z + f.y * b2.w;
  f = cvt2lo(q.w); acc += f.x * b3.x + f.y * b3.y;
  f = cvt2hi(q.w); acc += f.x * b3.z + f.y * b3.w;
  return acc;
}

// acc[0..15] += f32(q bytes) * av
__device__ __forceinline__ void fma16(float* acc, uint4 q, float av) {
  v2f f;
  f = cvt2lo(q.x); acc[0]  += f.x * av; acc[1]  += f.y * av;
  f = cvt2hi(q.x); acc[2]  += f.x * av; acc[3]  += f.y * av;
  f = cvt2lo(q.y); acc[4]  += f.x * av; acc[5]  += f.y * av;
  f = cvt2hi(q.y); acc[6]  += f.x * av; acc[7]  += f.y * av;
  f = cvt2lo(q.z); acc[8]  += f.x * av; acc[9]  += f.y * av;
  f = cvt2hi(q.z); acc[10] += f.x * av; acc[11] += f.y * av;
  f = cvt2lo(q.w); acc[12] += f.x * av; acc[13] += f.y * av;
  f = cvt2hi(q.w); acc[14] += f.x * av; acc[15] += f.y * av;
}

// ---- Prologue: K8 = e4m3(256 * exp(-C/gamma)), 4 elems/thread -------------
__global__ __launch_bounds__(1024) void prologue_k(const float4* __restrict__ C,
                                                   unsigned* __restrict__ K8) {
  int tid = blockIdx.x * 1024 + threadIdx.x;      // 16384 blocks
  float4 c = C[tid];
  unsigned p = 0;
  p = __builtin_amdgcn_cvt_pk_fp8_f32(exp2f(c.x * SCALE + KLOG2),
                                      exp2f(c.y * SCALE + KLOG2), p, false);
  p = __builtin_amdgcn_cvt_pk_fp8_f32(exp2f(c.z * SCALE + KLOG2),
                                      exp2f(c.w * SCALE + KLOG2), p, true);
  K8[tid] = p;
}

// ---- Phase A: y = K~ b (row GEMV); a = (d+eps)/y; zero zcur ---------------
// 256 blocks x 1024 threads; block = 32 rows; wave handles 2 rows.
// b stored in LDS as padded float4 granules: granule g lives at g + (g>>4)
// -> stride-64B lane reads hit the 8-access/bank floor (conflict-free).
template <bool USEK>
__global__ __launch_bounds__(1024) void phaseA_k(const void* __restrict__ Kp,
                                                 const float* __restrict__ zprev,
                                                 const float* __restrict__ s,
                                                 const float* __restrict__ d,
                                                 float* __restrict__ a,
                                                 float* __restrict__ zcur) {
  __shared__ float4 bs4[2176];   // 2048 granules + 128 pad
  int t = threadIdx.x;
  {
    int g0 = 2 * t, g1 = 2 * t + 1;
    float4 ba, bb;
    if (zprev) {
      const float4* zp4 = (const float4*)zprev;
      const float4* s4 = (const float4*)s;
      float4 za = zp4[g0], zb = zp4[g1];
      float4 sa = s4[g0], sb = s4[g1];
      ba.x = (sa.x + EPS) / za.x; ba.y = (sa.y + EPS) / za.y;
      ba.z = (sa.z + EPS) / za.z; ba.w = (sa.w + EPS) / za.w;
      bb.x = (sb.x + EPS) / zb.x; bb.y = (sb.y + EPS) / zb.y;
      bb.z = (sb.z + EPS) / zb.z; bb.w = (sb.w + EPS) / zb.w;
    } else {
      const float E = 2.718281828459045f;
      ba = float4{E, E, E, E}; bb = ba;
    }
    bs4[g0 + (g0 >> 4)] = ba;
    bs4[g1 + (g1 >> 4)] = bb;
  }
  if (t < 32) zcur[blockIdx.x * 32 + t] = 0.f;
  __syncthreads();

  int wave = t >> 6, lane = t & 63;
  for (int rr = wave; rr < 32; rr += 16) {
    int row = blockIdx.x * 32 + rr;
    float acc = 0.f;
    if (USEK) {
      const uint4* Kr = (const uint4*)Kp + (size_t)row * 512;
      uint4 q[8];
      #pragma unroll
      for (int k = 0; k < 8; k++) q[k] = Kr[k * 64 + lane];
      #pragma unroll
      for (int k = 0; k < 8; k++) {
        int idx = k * 64 + lane;
        int g = idx * 4;
        const float4* bp = &bs4[g + (g >> 4)];
        acc += dot16(q[k], bp[0], bp[1], bp[2], bp[3]);
      }
    } else {
      const float4* Cr = (const float4*)Kp + (size_t)row * 2048;
      for (int k = 0; k < 8; k++) {
        int idx = k * 64 + lane;
        int g = idx * 4;
        const float4* bp = &bs4[g + (g >> 4)];
        #pragma unroll
        for (int m = 0; m < 4; m++) {
          float4 c = Cr[idx * 4 + m];
          float4 b = bp[m];
          acc += exp2f(c.x * SCALE + KLOG2) * b.x
               + exp2f(c.y * SCALE + KLOG2) * b.y
               + exp2f(c.z * SCALE + KLOG2) * b.z
               + exp2f(c.w * SCALE + KLOG2) * b.w;
        }
      }
    }
    #pragma unroll
    for (int off = 32; off; off >>= 1) acc += __shfl_down(acc, off, 64);
    if (lane == 0) a[row] = (d[row] + EPS) / acc;
  }
}

// ---- Phase B: z = K~^T a (col GEMV) ---------------------------------------
// 256 blocks = 4 col-groups (2048 cols) x 64 row-groups (128 rows).
// Thread: ct = t&127 (16 cols via one uint4), rl = t>>7 (16 rows each).
// Reduce 8 rl-groups via LDS ds_add_f32 into transposed zp[m*128+ct]
// (conflict-free), then <=64 global atomics per zcur address.
template <bool USEK>
__global__ __launch_bounds__(1024) void phaseB_k(const void* __restrict__ Kp,
                                                 const float* __restrict__ a,
                                                 float* __restrict__ zcur) {
  __shared__ float as_[128];
  __shared__ float zp[2048];
  int t = threadIdx.x;
  int cg = blockIdx.x & 3, rg = blockIdx.x >> 2;
  if (t < 128) as_[t] = a[rg * 128 + t];
  if (t < 512) ((float4*)zp)[t] = float4{0.f, 0.f, 0.f, 0.f};
  __syncthreads();

  int ct = t & 127, rl = t >> 7;
  float acc[16];
  #pragma unroll
  for (int k = 0; k < 16; k++) acc[k] = 0.f;

  if (USEK) {
    const uint4* Kb = (const uint4*)Kp;
    int base = cg * 128 + ct;
    #pragma unroll
    for (int rq = 0; rq < 4; rq++) {
      int r0 = rg * 128 + rl * 16 + rq * 4;
      uint4 q0 = Kb[(size_t)(r0 + 0) * 512 + base];
      uint4 q1 = Kb[(size_t)(r0 + 1) * 512 + base];
      uint4 q2 = Kb[(size_t)(r0 + 2) * 512 + base];
      uint4 q3 = Kb[(size_t)(r0 + 3) * 512 + base];
      fma16(acc, q0, as_[rl * 16 + rq * 4 + 0]);
      fma16(acc, q1, as_[rl * 16 + rq * 4 + 1]);
      fma16(acc, q2, as_[rl * 16 + rq * 4 + 2]);
      fma16(acc, q3, as_[rl * 16 + rq * 4 + 3]);
    }
  } else {
    const float4* Cq = (const float4*)Kp;
    int base4 = (cg * 128 + ct) * 4;
    for (int rq = 0; rq < 4; rq++) {
      #pragma unroll
      for (int j = 0; j < 4; j++) {
        int r = rg * 128 + rl * 16 + rq * 4 + j;
        float av = as_[rl * 16 + rq * 4 + j];
        const float4* Cr = Cq + (size_t)r * 2048 + base4;
        #pragma unroll
        for (int m = 0; m < 4; m++) {
          float4 c = Cr[m];
          acc[m * 4 + 0] += exp2f(c.x * SCALE + KLOG2) * av;
          acc[m * 4 + 1] += exp2f(c.y * SCALE + KLOG2) * av;
          acc[m * 4 + 2] += exp2f(c.z * SCALE + KLOG2) * av;
          acc[m * 4 + 3] += exp2f(c.w * SCALE + KLOG2) * av;
        }
      }
    }
  }

  #pragma unroll
  for (int m = 0; m < 16; m++) atomicAdd(&zp[m * 128 + ct], acc[m]);
  __syncthreads();

  for (int jj = t; jj < 2048; jj += 1024)
    atomicAdd(&zcur[cg * 2048 + jj], zp[(jj & 15) * 128 + (jj >> 4)]);
}

// ---- Epilogue: P = 256 * a_i * exp(-C/gamma) * b_j (fp32 C for precision) -
__global__ __launch_bounds__(1024) void epilogue_k(const float4* __restrict__ C,
                                                   const float* __restrict__ a,
                                                   const float* __restrict__ zlast,
                                                   const float* __restrict__ s,
                                                   float4* __restrict__ out) {
  __shared__ float4 bs4[2048];
  int t = threadIdx.x;
  {
    const float4* s4 = (const float4*)s;
    const float4* z4 = (const float4*)zlast;
    float4 sa = s4[2 * t], sb = s4[2 * t + 1];
    float4 za = z4[2 * t], zb = z4[2 * t + 1];
    float4 ba, bb;
    ba.x = (sa.x + EPS) / za.x; ba.y = (sa.y + EPS) / za.y;
    ba.z = (sa.z + EPS) / za.z; ba.w = (sa.w + EPS) / za.w;
    bb.x = (sb.x + EPS) / zb.x; bb.y = (sb.y + EPS) / zb.y;
    bb.z = (sb.z + EPS) / zb.z; bb.w = (sb.w + EPS) / zb.w;
    bs4[2 * t] = ba; bs4[2 * t + 1] = bb;
  }
  __syncthreads();
  int wave = t >> 6, lane = t & 63;
  for (int rr = wave; rr < 32; rr += 16) {
    int row = blockIdx.x * 32 + rr;
    float av = a[row] * KSCALE;
    const float4* Crow = C + (size_t)row * 2048;
    float4* Orow = out + (size_t)row * 2048;
    for (int k = 0; k < 32; k++) {
      int idx = k * 64 + lane;
      float4 c = Crow[idx];
      float4 b = bs4[idx];
      float4 p;
      p.x = av * b.x * exp2f(c.x * SCALE);
      p.y = av * b.y * exp2f(c.y * SCALE);
      p.z = av * b.z * exp2f(c.z * SCALE);
      p.w = av * b.w * exp2f(c.w * SCALE);
      Orow[idx] = p;
    }
  }
}

extern "C" void kernel_launch(void* const* d_in, const int* in_sizes, int n_in,
                              void* d_out, int out_size, void* d_ws, size_t ws_size,
                              hipStream_t stream) {
  const float* C = (const float*)d_in[0];
  const float* d = (const float*)d_in[1];
  const float* s = (const float*)d_in[2];

  float* z0 = (float*)d_ws;
  float* z1 = z0 + NDIM;
  float* a  = z1 + NDIM;
  char* kbase = (char*)d_ws + 131072;
  size_t kneed = 131072 + (size_t)NDIM * NDIM;   // vectors + fp8 K
  bool usek = ws_size >= kneed;

  if (usek) {
    prologue_k<<<16384, 1024, 0, stream>>>((const float4*)C, (unsigned*)kbase);
  }
  const void* Kp = usek ? (const void*)kbase : (const void*)C;

  for (int it = 0; it < NSTEPS; ++it) {
    float* zc = (it & 1) ? z1 : z0;
    const float* zp = (it == 0) ? nullptr : ((it & 1) ? z0 : z1);
    if (usek) {
      phaseA_k<true><<<256, 1024, 0, stream>>>(Kp, zp, s, d, a, zc);
      phaseB_k<true><<<256, 1024, 0, stream>>>(Kp, a, zc);
    } else {
      phaseA_k<false><<<256, 1024, 0, stream>>>(Kp, zp, s, d, a, zc);
      phaseB_k<false><<<256, 1024, 0, stream>>>(Kp, a, zc);
    }
  }
  const float* zlast = ((NSTEPS - 1) & 1) ? z1 : z0;
  epilogue_k<<<256, 1024, 0, stream>>>((const float4*)C, a, zlast, s, (float4*)d_out);
}